// Round 1
// baseline (1544.832 us; speedup 1.0000x reference)
//
#include <hip/hip_runtime.h>

#define NN 100000
#define EE 1600000
#define ETOT (EE + NN)
#define FF 48
#define NEG 0.2f

// ---------------- CSR build ----------------

__global__ void k_init_count(int* __restrict__ c) {
    int i = blockIdx.x * 256 + threadIdx.x;
    if (i < NN) c[i] = 1;  // self-loop
}

__global__ void k_count(const int* __restrict__ ei, int* __restrict__ c) {
    int i = blockIdx.x * 256 + threadIdx.x;
    if (i < EE) atomicAdd(&c[ei[EE + i]], 1);
}

// chunk = 2048 elems/block, 256 threads x 8
__global__ void k_scan1(const int* __restrict__ c, int* __restrict__ off, int* __restrict__ bsum) {
    __shared__ int lds[256];
    int t = threadIdx.x;
    int base = blockIdx.x * 2048 + t * 8;
    int v[8];
    int sum = 0;
#pragma unroll
    for (int j = 0; j < 8; j++) {
        int idx = base + j;
        int x = (idx < NN) ? c[idx] : 0;
        sum += x;
        v[j] = sum;
    }
    lds[t] = sum;
    __syncthreads();
    for (int o = 1; o < 256; o <<= 1) {
        int x = (t >= o) ? lds[t - o] : 0;
        __syncthreads();
        lds[t] += x;
        __syncthreads();
    }
    int pre = (t > 0) ? lds[t - 1] : 0;
#pragma unroll
    for (int j = 0; j < 8; j++) {
        int idx = base + j;
        if (idx < NN) off[idx + 1] = v[j] + pre;
    }
    if (t == 255) bsum[blockIdx.x] = lds[255];
}

__global__ void k_scan2(int* __restrict__ bsum, int nb) {
    if (threadIdx.x == 0) {
        int acc = 0;
        for (int i = 0; i < nb; i++) {
            int t = bsum[i];
            bsum[i] = acc;
            acc += t;
        }
    }
}

__global__ void k_scan3(int* __restrict__ off, const int* __restrict__ bsum) {
    int i = blockIdx.x * 256 + threadIdx.x;
    if (i < NN) off[i + 1] += bsum[i >> 11];
    if (i == 0) off[0] = 0;
}

__global__ void k_copy(int* __restrict__ cur, const int* __restrict__ off) {
    int i = blockIdx.x * 256 + threadIdx.x;
    if (i < NN) cur[i] = off[i];
}

__global__ void k_fill(const int* __restrict__ ei, int* __restrict__ cur, int* __restrict__ ssrc) {
    int i = blockIdx.x * 256 + threadIdx.x;
    if (i >= ETOT) return;
    int s, d;
    if (i < EE) {
        s = ei[i];
        d = ei[EE + i];
    } else {
        s = i - EE;
        d = s;
    }
    int pos = atomicAdd(&cur[d], 1);
    ssrc[pos] = s;
}

// ---------------- per-layer kernels ----------------

// h[row, f] = sum_k in[row, k] * W[k, f]; 4 rows x 1 col per thread, W in LDS
template <int K>
__global__ __launch_bounds__(256) void k_gemm(const float* __restrict__ in,
                                              const float* __restrict__ W,
                                              float* __restrict__ h) {
    __shared__ float Wl[K * FF];
    int t = threadIdx.x;
    for (int i = t; i < K * FF; i += 256) Wl[i] = W[i];
    __syncthreads();
    int gid = blockIdx.x * 256 + t;
    int f = gid % FF, rq = gid / FF;
    if (rq >= NN / 4) return;
    const float* x0 = in + (size_t)rq * 4 * K;
    float a0 = 0.f, a1 = 0.f, a2 = 0.f, a3 = 0.f;
    for (int k = 0; k < K; k++) {
        float w = Wl[k * FF + f];
        a0 = fmaf(x0[k], w, a0);
        a1 = fmaf(x0[K + k], w, a1);
        a2 = fmaf(x0[2 * K + k], w, a2);
        a3 = fmaf(x0[3 * K + k], w, a3);
    }
    size_t o = (size_t)rq * 4 * FF + f;
    h[o] = a0;
    h[o + FF] = a1;
    h[o + 2 * FF] = a2;
    h[o + 3 * FF] = a3;
}

__global__ void k_alpha(const float* __restrict__ h, const float* __restrict__ a_s,
                        const float* __restrict__ a_d, float* __restrict__ as_,
                        float* __restrict__ ad_) {
    int i = blockIdx.x * 256 + threadIdx.x;
    if (i >= NN) return;
    const float4* hr = (const float4*)(h + (size_t)i * FF);
    const float4* av = (const float4*)a_s;
    const float4* bv = (const float4*)a_d;
    float s = 0.f, d = 0.f;
#pragma unroll
    for (int q = 0; q < FF / 4; q++) {
        float4 v = hr[q];
        float4 a = av[q];
        float4 b = bv[q];
        s += v.x * a.x + v.y * a.y + v.z * a.z + v.w * a.w;
        d += v.x * b.x + v.y * b.y + v.z * b.z + v.w * b.w;
    }
    as_[i] = s;
    ad_[i] = d;
}

// one wave (64 lanes) per destination node; lanes 0..47 own feature f
__global__ __launch_bounds__(256) void k_aggr(const float* __restrict__ h,
                                              const float* __restrict__ as_,
                                              const float* __restrict__ ad_,
                                              const int* __restrict__ off,
                                              const int* __restrict__ ssrc,
                                              const float* __restrict__ bias,
                                              float* __restrict__ out) {
    int wave = threadIdx.x >> 6;
    int lane = threadIdx.x & 63;
    int d = blockIdx.x * 4 + wave;
    if (d >= NN) return;
    int beg = off[d], end = off[d + 1];
    float add = ad_[d];

    // pass 1: segment max of leaky_relu(as[src] + ad[d]), edge-parallel over lanes
    float m = -1e30f;
    for (int i = beg + lane; i < end; i += 64) {
        float e = as_[ssrc[i]] + add;
        e = (e > 0.f) ? e : NEG * e;
        m = fmaxf(m, e);
    }
#pragma unroll
    for (int o = 32; o; o >>= 1) m = fmaxf(m, __shfl_xor(m, o));

    // pass 2: serial over edges; all lanes compute p (redundant), lane f accumulates feature f
    float acc = 0.f, s = 0.f;
    int f = lane;
    for (int i = beg; i < end; i++) {
        int src = ssrc[i];
        float e = as_[src] + add;
        e = (e > 0.f) ? e : NEG * e;
        float p = __expf(e - m);
        s += p;
        if (f < FF) acc = fmaf(p, h[(size_t)src * FF + f], acc);
    }
    if (f < FF) {
        float v = acc / fmaxf(s, 1e-16f) + bias[f];
        v = (v > 0.f) ? v : (__expf(v) - 1.0f);  // ELU
        out[(size_t)d * FF + f] = v;
    }
}

// ---------------- launcher ----------------

static inline size_t alup(size_t x) { return (x + 255) & ~(size_t)255; }

extern "C" void kernel_launch(void* const* d_in, const int* in_sizes, int n_in,
                              void* d_out, int out_size, void* d_ws, size_t ws_size,
                              hipStream_t stream) {
    const float* x = (const float*)d_in[0];
    const int* ei = (const int*)d_in[1];
    const float* W0 = (const float*)d_in[2];
    const float* Wr = (const float*)d_in[3];
    const float* As = (const float*)d_in[4];
    const float* Ad = (const float*)d_in[5];
    const float* B = (const float*)d_in[6];
    float* out = (float*)d_out;

    char* p = (char*)d_ws;
    int* off = (int*)p;      p += alup((NN + 1) * sizeof(int));
    int* cur = (int*)p;      p += alup(NN * sizeof(int));       // count, then cursor
    int* bsum = (int*)p;     p += alup(64 * sizeof(int));
    int* ssrc = (int*)p;     p += alup((size_t)ETOT * sizeof(int));
    float* htmp = (float*)p; p += alup((size_t)NN * FF * sizeof(float));
    float* act = (float*)p;  p += alup((size_t)NN * FF * sizeof(float));
    float* as_ = (float*)p;  p += alup(NN * sizeof(float));
    float* ad_ = (float*)p;  p += alup(NN * sizeof(float));

    int gN = (NN + 255) / 256;
    int gE = (EE + 255) / 256;
    int gET = (ETOT + 255) / 256;
    int nb = (NN + 2047) / 2048;

    k_init_count<<<gN, 256, 0, stream>>>(cur);
    k_count<<<gE, 256, 0, stream>>>(ei, cur);
    k_scan1<<<nb, 256, 0, stream>>>(cur, off, bsum);
    k_scan2<<<1, 64, 0, stream>>>(bsum, nb);
    k_scan3<<<gN, 256, 0, stream>>>(off, bsum);
    k_copy<<<gN, 256, 0, stream>>>(cur, off);
    k_fill<<<gET, 256, 0, stream>>>(ei, cur, ssrc);

    int gGemm = (25000 * 48 + 255) / 256;
    for (int l = 0; l < 5; l++) {
        if (l == 0)
            k_gemm<100><<<gGemm, 256, 0, stream>>>(x, W0, htmp);
        else
            k_gemm<48><<<gGemm, 256, 0, stream>>>(act, Wr + (size_t)(l - 1) * 48 * 48, htmp);
        k_alpha<<<gN, 256, 0, stream>>>(htmp, As + l * 48, Ad + l * 48, as_, ad_);
        k_aggr<<<(NN + 3) / 4, 256, 0, stream>>>(htmp, as_, ad_, off, ssrc, B + l * 48,
                                                 (l == 4) ? out : act);
    }
}

// Round 4
// 789.427 us; speedup vs baseline: 1.9569x; 1.9569x over previous
//
#include <hip/hip_runtime.h>

#define NN 100000
#define EE 1600000
#define ETOT (EE + NN)
#define FF 48
#define NEG 0.2f

// ---------------- CSR build ----------------

__global__ void k_init_count(int* __restrict__ c) {
    int i = blockIdx.x * 256 + threadIdx.x;
    if (i < NN) c[i] = 1;  // self-loop
}

__global__ void k_count(const int* __restrict__ ei, int* __restrict__ c) {
    int i = blockIdx.x * 256 + threadIdx.x;
    if (i < EE) atomicAdd(&c[ei[EE + i]], 1);
}

// chunk = 2048 elems/block, 256 threads x 8
__global__ void k_scan1(const int* __restrict__ c, int* __restrict__ off, int* __restrict__ bsum) {
    __shared__ int lds[256];
    int t = threadIdx.x;
    int base = blockIdx.x * 2048 + t * 8;
    int v[8];
    int sum = 0;
#pragma unroll
    for (int j = 0; j < 8; j++) {
        int idx = base + j;
        int x = (idx < NN) ? c[idx] : 0;
        sum += x;
        v[j] = sum;
    }
    lds[t] = sum;
    __syncthreads();
    for (int o = 1; o < 256; o <<= 1) {
        int x = (t >= o) ? lds[t - o] : 0;
        __syncthreads();
        lds[t] += x;
        __syncthreads();
    }
    int pre = (t > 0) ? lds[t - 1] : 0;
#pragma unroll
    for (int j = 0; j < 8; j++) {
        int idx = base + j;
        if (idx < NN) off[idx + 1] = v[j] + pre;
    }
    if (t == 255) bsum[blockIdx.x] = lds[255];
}

__global__ void k_scan2(int* __restrict__ bsum, int nb) {
    if (threadIdx.x == 0) {
        int acc = 0;
        for (int i = 0; i < nb; i++) {
            int t = bsum[i];
            bsum[i] = acc;
            acc += t;
        }
    }
}

__global__ void k_scan3(int* __restrict__ off, const int* __restrict__ bsum) {
    int i = blockIdx.x * 256 + threadIdx.x;
    if (i < NN) off[i + 1] += bsum[i >> 11];
    if (i == 0) off[0] = 0;
}

__global__ void k_copy(int* __restrict__ cur, const int* __restrict__ off) {
    int i = blockIdx.x * 256 + threadIdx.x;
    if (i < NN) cur[i] = off[i];
}

__global__ void k_fill(const int* __restrict__ ei, int* __restrict__ cur, int* __restrict__ ssrc) {
    int i = blockIdx.x * 256 + threadIdx.x;
    if (i >= ETOT) return;
    int s, d;
    if (i < EE) {
        s = ei[i];
        d = ei[EE + i];
    } else {
        s = i - EE;
        d = s;
    }
    int pos = atomicAdd(&cur[d], 1);
    ssrc[pos] = s;
}

// ---------------- per-layer kernels (bit-identical to R1) ----------------

template <int K>
__global__ __launch_bounds__(256) void k_gemm(const float* __restrict__ in,
                                              const float* __restrict__ W,
                                              float* __restrict__ h) {
    __shared__ float Wl[K * FF];
    int t = threadIdx.x;
    for (int i = t; i < K * FF; i += 256) Wl[i] = W[i];
    __syncthreads();
    int gid = blockIdx.x * 256 + t;
    int f = gid % FF, rq = gid / FF;
    if (rq >= NN / 4) return;
    const float* x0 = in + (size_t)rq * 4 * K;
    float a0 = 0.f, a1 = 0.f, a2 = 0.f, a3 = 0.f;
    for (int k = 0; k < K; k++) {
        float w = Wl[k * FF + f];
        a0 = fmaf(x0[k], w, a0);
        a1 = fmaf(x0[K + k], w, a1);
        a2 = fmaf(x0[2 * K + k], w, a2);
        a3 = fmaf(x0[3 * K + k], w, a3);
    }
    size_t o = (size_t)rq * 4 * FF + f;
    h[o] = a0;
    h[o + FF] = a1;
    h[o + 2 * FF] = a2;
    h[o + 3 * FF] = a3;
}

__global__ void k_alpha(const float* __restrict__ h, const float* __restrict__ a_s,
                        const float* __restrict__ a_d, float* __restrict__ as_,
                        float* __restrict__ ad_) {
    int i = blockIdx.x * 256 + threadIdx.x;
    if (i >= NN) return;
    const float4* hr = (const float4*)(h + (size_t)i * FF);
    const float4* av = (const float4*)a_s;
    const float4* bv = (const float4*)a_d;
    float s = 0.f, d = 0.f;
#pragma unroll
    for (int q = 0; q < FF / 4; q++) {
        float4 v = hr[q];
        float4 a = av[q];
        float4 b = bv[q];
        s += v.x * a.x + v.y * a.y + v.z * a.z + v.w * a.w;
        d += v.x * b.x + v.y * b.y + v.z * b.z + v.w * b.w;
    }
    as_[i] = s;
    ad_[i] = d;
}

// one wave per destination node; lane f in 0..47 owns feature f (R1 mapping).
// Fast path (deg<=64, always true here): lane i computes p_i once; (p_i,src_i)
// broadcast via wave-uniform __shfl in a UNIFORM-trip-count loop, unrolled x4
// so 4 independent h-row gathers are in flight. Accumulation order and formulas
// are bit-identical to the R1 kernel that passed.
__global__ __launch_bounds__(256) void k_aggr(const float* __restrict__ h,
                                              const float* __restrict__ as_,
                                              const float* __restrict__ ad_,
                                              const int* __restrict__ off,
                                              const int* __restrict__ ssrc,
                                              const float* __restrict__ bias,
                                              float* __restrict__ out) {
    int wave = threadIdx.x >> 6;
    int lane = threadIdx.x & 63;
    int d = blockIdx.x * 4 + wave;
    if (d >= NN) return;
    int beg = off[d], end = off[d + 1];
    int deg = end - beg;
    float add = ad_[d];
    int f = lane;

    float acc = 0.f, s = 0.f;

    if (deg <= 64) {
        int src = 0;
        float e = -1e30f;
        if (lane < deg) {
            src = ssrc[beg + lane];
            float t = as_[src] + add;
            e = (t > 0.f) ? t : NEG * t;
        }
        float m = e;
#pragma unroll
        for (int o = 32; o; o >>= 1) m = fmaxf(m, __shfl_xor(m, o));
        float p = (lane < deg) ? __expf(e - m) : 0.f;

        int i = 0;
        for (; i + 4 <= deg; i += 4) {
            float p0 = __shfl(p, i), p1 = __shfl(p, i + 1);
            float p2 = __shfl(p, i + 2), p3 = __shfl(p, i + 3);
            int s0 = __shfl(src, i), s1 = __shfl(src, i + 1);
            int s2 = __shfl(src, i + 2), s3 = __shfl(src, i + 3);
            float h0 = 0.f, h1 = 0.f, h2 = 0.f, h3 = 0.f;
            if (f < FF) {
                h0 = h[(size_t)s0 * FF + f];
                h1 = h[(size_t)s1 * FF + f];
                h2 = h[(size_t)s2 * FF + f];
                h3 = h[(size_t)s3 * FF + f];
            }
            s += p0; s += p1; s += p2; s += p3;
            if (f < FF) {
                acc = fmaf(p0, h0, acc);
                acc = fmaf(p1, h1, acc);
                acc = fmaf(p2, h2, acc);
                acc = fmaf(p3, h3, acc);
            }
        }
        for (; i < deg; i++) {
            float pi = __shfl(p, i);
            int si = __shfl(src, i);
            s += pi;
            if (f < FF) acc = fmaf(pi, h[(size_t)si * FF + f], acc);
        }
    } else {
        // general path (never taken for this graph): R1's serial version
        float m = -1e30f;
        for (int i = beg + lane; i < end; i += 64) {
            float t = as_[ssrc[i]] + add;
            t = (t > 0.f) ? t : NEG * t;
            m = fmaxf(m, t);
        }
#pragma unroll
        for (int o = 32; o; o >>= 1) m = fmaxf(m, __shfl_xor(m, o));
        for (int i = beg; i < end; i++) {
            int src = ssrc[i];
            float e = as_[src] + add;
            e = (e > 0.f) ? e : NEG * e;
            float pp = __expf(e - m);
            s += pp;
            if (f < FF) acc = fmaf(pp, h[(size_t)src * FF + f], acc);
        }
    }

    if (f < FF) {
        float v = acc / fmaxf(s, 1e-16f) + bias[f];
        v = (v > 0.f) ? v : (__expf(v) - 1.0f);  // ELU
        out[(size_t)d * FF + f] = v;
    }
}

// ---------------- launcher ----------------

static inline size_t alup(size_t x) { return (x + 255) & ~(size_t)255; }

extern "C" void kernel_launch(void* const* d_in, const int* in_sizes, int n_in,
                              void* d_out, int out_size, void* d_ws, size_t ws_size,
                              hipStream_t stream) {
    const float* x = (const float*)d_in[0];
    const int* ei = (const int*)d_in[1];
    const float* W0 = (const float*)d_in[2];
    const float* Wr = (const float*)d_in[3];
    const float* As = (const float*)d_in[4];
    const float* Ad = (const float*)d_in[5];
    const float* B = (const float*)d_in[6];
    float* out = (float*)d_out;

    char* p = (char*)d_ws;
    int* off = (int*)p;      p += alup((NN + 1) * sizeof(int));
    int* cur = (int*)p;      p += alup(NN * sizeof(int));       // count, then cursor
    int* bsum = (int*)p;     p += alup(64 * sizeof(int));
    int* ssrc = (int*)p;     p += alup((size_t)ETOT * sizeof(int));
    float* htmp = (float*)p; p += alup((size_t)NN * FF * sizeof(float));
    float* act = (float*)p;  p += alup((size_t)NN * FF * sizeof(float));
    float* as_ = (float*)p;  p += alup(NN * sizeof(float));
    float* ad_ = (float*)p;  p += alup(NN * sizeof(float));

    int gN = (NN + 255) / 256;
    int gE = (EE + 255) / 256;
    int gET = (ETOT + 255) / 256;
    int nb = (NN + 2047) / 2048;

    k_init_count<<<gN, 256, 0, stream>>>(cur);
    k_count<<<gE, 256, 0, stream>>>(ei, cur);
    k_scan1<<<nb, 256, 0, stream>>>(cur, off, bsum);
    k_scan2<<<1, 64, 0, stream>>>(bsum, nb);
    k_scan3<<<gN, 256, 0, stream>>>(off, bsum);
    k_copy<<<gN, 256, 0, stream>>>(cur, off);
    k_fill<<<gET, 256, 0, stream>>>(ei, cur, ssrc);

    int gGemm = (25000 * 48 + 255) / 256;
    for (int l = 0; l < 5; l++) {
        if (l == 0)
            k_gemm<100><<<gGemm, 256, 0, stream>>>(x, W0, htmp);
        else
            k_gemm<48><<<gGemm, 256, 0, stream>>>(act, Wr + (size_t)(l - 1) * 48 * 48, htmp);
        k_alpha<<<gN, 256, 0, stream>>>(htmp, As + l * 48, Ad + l * 48, as_, ad_);
        k_aggr<<<(NN + 3) / 4, 256, 0, stream>>>(htmp, as_, ad_, off, ssrc, B + l * 48,
                                                 (l == 4) ? out : act);
    }
}

// Round 5
// 640.718 us; speedup vs baseline: 2.4111x; 1.2321x over previous
//
#include <hip/hip_runtime.h>

#define NN 100000
#define EE 1600000
#define ETOT (EE + NN)
#define FF 48
#define NEG 0.2f
#define BSH 9
#define BNODES 512                       // nodes per bucket = 1<<BSH
#define NBUK ((NN + BNODES - 1) / BNODES)  // 196
#define TILE 2048

// ---------------- bucketed CSR build ----------------

// bucket histogram: LDS hist then one global atomic per bucket per block
__global__ __launch_bounds__(256) void k_bhist(const int* __restrict__ ei,
                                               int* __restrict__ bcnt) {
    __shared__ int h[256];
    int t = threadIdx.x;
    h[t] = 0;
    __syncthreads();
    for (int i = blockIdx.x * 256 + t; i < ETOT; i += gridDim.x * 256) {
        int dd = (i < EE) ? ei[EE + i] : (i - EE);
        atomicAdd(&h[dd >> BSH], 1);
    }
    __syncthreads();
    if (h[t] > 0) atomicAdd(&bcnt[t], h[t]);
}

// exclusive scan of 196 bucket counts (padded to 256); boff[t]=excl, boff[NBUK]=total
__global__ void k_bscan(const int* __restrict__ bcnt, int* __restrict__ boff,
                        int* __restrict__ bcur) {
    __shared__ int sb[256];
    int t = threadIdx.x;
    int v = (t < NBUK) ? bcnt[t] : 0;
    sb[t] = v;
    __syncthreads();
    for (int o = 1; o < 256; o <<= 1) {
        int x = (t >= o) ? sb[t - o] : 0;
        __syncthreads();
        sb[t] += x;
        __syncthreads();
    }
    int excl = sb[t] - v;
    boff[t] = excl;  // t==NBUK gets total (v=0 there)
    bcur[t] = excl;
}

// tile of 2048 edges: LDS-bin by bucket, stage ordered, copy out piecewise-contiguous
__global__ __launch_bounds__(256) void k_bscatter(const int* __restrict__ ei,
                                                  int* __restrict__ bcur,
                                                  int2* __restrict__ pairs) {
    __shared__ int hist[256], incl[256], exc[256], curv[256], gb[256];
    __shared__ int2 stage[TILE];
    __shared__ int staddr[TILE];
    int t = threadIdx.x;
    hist[t] = 0;
    __syncthreads();
    int base = blockIdx.x * TILE;
    int s[8], d[8], b[8];
#pragma unroll
    for (int j = 0; j < 8; j++) {
        int i = base + t + j * 256;
        if (i < ETOT) {
            int ss, dd;
            if (i < EE) { ss = ei[i]; dd = ei[EE + i]; }
            else { ss = i - EE; dd = ss; }
            s[j] = ss; d[j] = dd; b[j] = dd >> BSH;
            atomicAdd(&hist[b[j]], 1);
        } else {
            b[j] = -1;
        }
    }
    __syncthreads();
    int hv = hist[t];
    incl[t] = hv;
    __syncthreads();
    for (int o = 1; o < 256; o <<= 1) {
        int x = (t >= o) ? incl[t - o] : 0;
        __syncthreads();
        incl[t] += x;
        __syncthreads();
    }
    int excl = incl[t] - hv;
    exc[t] = excl;
    curv[t] = excl;
    if (hv > 0) gb[t] = atomicAdd(&bcur[t], hv);
    __syncthreads();
    int total = incl[255];
#pragma unroll
    for (int j = 0; j < 8; j++) {
        if (b[j] >= 0) {
            int pos = atomicAdd(&curv[b[j]], 1);
            stage[pos] = make_int2(s[j], d[j]);
            staddr[pos] = gb[b[j]] + (pos - exc[b[j]]);
        }
    }
    __syncthreads();
    for (int i = t; i < total; i += 256) pairs[staddr[i]] = stage[i];
}

// one block per bucket: per-node histogram + scan -> off[], then localized scatter
__global__ __launch_bounds__(256) void k_bfill(const int2* __restrict__ pairs,
                                               const int* __restrict__ boff,
                                               int* __restrict__ off,
                                               int* __restrict__ ssrc) {
    __shared__ int cnt[BNODES], cu[BNODES], sb[256];
    int blk = blockIdx.x;
    int t = threadIdx.x;
    int n0 = blk << BSH;
    int beg = boff[blk], end = boff[blk + 1];
    cnt[t] = 0;
    cnt[t + 256] = 0;
    __syncthreads();
    for (int i = beg + t; i < end; i += 256) {
        atomicAdd(&cnt[pairs[i].y - n0], 1);
    }
    __syncthreads();
    int c0 = cnt[2 * t], c1 = cnt[2 * t + 1];
    sb[t] = c0 + c1;
    __syncthreads();
    for (int o = 1; o < 256; o <<= 1) {
        int x = (t >= o) ? sb[t - o] : 0;
        __syncthreads();
        sb[t] += x;
        __syncthreads();
    }
    int e2 = sb[t] - (c0 + c1);
    cu[2 * t] = e2;
    cu[2 * t + 1] = e2 + c0;
    int n1 = min(n0 + BNODES, NN);
    if (n0 + 2 * t < n1) off[n0 + 2 * t] = beg + e2;
    if (n0 + 2 * t + 1 < n1) off[n0 + 2 * t + 1] = beg + e2 + c0;
    if (blk == 0 && t == 0) off[NN] = ETOT;
    __syncthreads();
    for (int i = beg + t; i < end; i += 256) {
        int2 pr = pairs[i];
        int pos = atomicAdd(&cu[pr.y - n0], 1);
        ssrc[beg + pos] = pr.x;
    }
}

// ---------------- per-layer kernels (unchanged from R4) ----------------

template <int K>
__global__ __launch_bounds__(256) void k_gemm(const float* __restrict__ in,
                                              const float* __restrict__ W,
                                              float* __restrict__ h) {
    __shared__ float Wl[K * FF];
    int t = threadIdx.x;
    for (int i = t; i < K * FF; i += 256) Wl[i] = W[i];
    __syncthreads();
    int gid = blockIdx.x * 256 + t;
    int f = gid % FF, rq = gid / FF;
    if (rq >= NN / 4) return;
    const float* x0 = in + (size_t)rq * 4 * K;
    float a0 = 0.f, a1 = 0.f, a2 = 0.f, a3 = 0.f;
    for (int k = 0; k < K; k++) {
        float w = Wl[k * FF + f];
        a0 = fmaf(x0[k], w, a0);
        a1 = fmaf(x0[K + k], w, a1);
        a2 = fmaf(x0[2 * K + k], w, a2);
        a3 = fmaf(x0[3 * K + k], w, a3);
    }
    size_t o = (size_t)rq * 4 * FF + f;
    h[o] = a0;
    h[o + FF] = a1;
    h[o + 2 * FF] = a2;
    h[o + 3 * FF] = a3;
}

__global__ void k_alpha(const float* __restrict__ h, const float* __restrict__ a_s,
                        const float* __restrict__ a_d, float* __restrict__ as_,
                        float* __restrict__ ad_) {
    int i = blockIdx.x * 256 + threadIdx.x;
    if (i >= NN) return;
    const float4* hr = (const float4*)(h + (size_t)i * FF);
    const float4* av = (const float4*)a_s;
    const float4* bv = (const float4*)a_d;
    float s = 0.f, d = 0.f;
#pragma unroll
    for (int q = 0; q < FF / 4; q++) {
        float4 v = hr[q];
        float4 a = av[q];
        float4 b = bv[q];
        s += v.x * a.x + v.y * a.y + v.z * a.z + v.w * a.w;
        d += v.x * b.x + v.y * b.y + v.z * b.z + v.w * b.w;
    }
    as_[i] = s;
    ad_[i] = d;
}

// one wave per destination node; lane f in 0..47 owns feature f.
__global__ __launch_bounds__(256) void k_aggr(const float* __restrict__ h,
                                              const float* __restrict__ as_,
                                              const float* __restrict__ ad_,
                                              const int* __restrict__ off,
                                              const int* __restrict__ ssrc,
                                              const float* __restrict__ bias,
                                              float* __restrict__ out) {
    int wave = threadIdx.x >> 6;
    int lane = threadIdx.x & 63;
    int d = blockIdx.x * 4 + wave;
    if (d >= NN) return;
    int beg = off[d], end = off[d + 1];
    int deg = end - beg;
    float add = ad_[d];
    int f = lane;

    float acc = 0.f, s = 0.f;

    if (deg <= 64) {
        int src = 0;
        float e = -1e30f;
        if (lane < deg) {
            src = ssrc[beg + lane];
            float t = as_[src] + add;
            e = (t > 0.f) ? t : NEG * t;
        }
        float m = e;
#pragma unroll
        for (int o = 32; o; o >>= 1) m = fmaxf(m, __shfl_xor(m, o));
        float p = (lane < deg) ? __expf(e - m) : 0.f;

        int i = 0;
        for (; i + 4 <= deg; i += 4) {
            float p0 = __shfl(p, i), p1 = __shfl(p, i + 1);
            float p2 = __shfl(p, i + 2), p3 = __shfl(p, i + 3);
            int s0 = __shfl(src, i), s1 = __shfl(src, i + 1);
            int s2 = __shfl(src, i + 2), s3 = __shfl(src, i + 3);
            float h0 = 0.f, h1 = 0.f, h2 = 0.f, h3 = 0.f;
            if (f < FF) {
                h0 = h[(size_t)s0 * FF + f];
                h1 = h[(size_t)s1 * FF + f];
                h2 = h[(size_t)s2 * FF + f];
                h3 = h[(size_t)s3 * FF + f];
            }
            s += p0; s += p1; s += p2; s += p3;
            if (f < FF) {
                acc = fmaf(p0, h0, acc);
                acc = fmaf(p1, h1, acc);
                acc = fmaf(p2, h2, acc);
                acc = fmaf(p3, h3, acc);
            }
        }
        for (; i < deg; i++) {
            float pi = __shfl(p, i);
            int si = __shfl(src, i);
            s += pi;
            if (f < FF) acc = fmaf(pi, h[(size_t)si * FF + f], acc);
        }
    } else {
        float m = -1e30f;
        for (int i = beg + lane; i < end; i += 64) {
            float t = as_[ssrc[i]] + add;
            t = (t > 0.f) ? t : NEG * t;
            m = fmaxf(m, t);
        }
#pragma unroll
        for (int o = 32; o; o >>= 1) m = fmaxf(m, __shfl_xor(m, o));
        for (int i = beg; i < end; i++) {
            int src = ssrc[i];
            float e = as_[src] + add;
            e = (e > 0.f) ? e : NEG * e;
            float pp = __expf(e - m);
            s += pp;
            if (f < FF) acc = fmaf(pp, h[(size_t)src * FF + f], acc);
        }
    }

    if (f < FF) {
        float v = acc / fmaxf(s, 1e-16f) + bias[f];
        v = (v > 0.f) ? v : (__expf(v) - 1.0f);  // ELU
        out[(size_t)d * FF + f] = v;
    }
}

// ---------------- launcher ----------------

static inline size_t alup(size_t x) { return (x + 255) & ~(size_t)255; }

extern "C" void kernel_launch(void* const* d_in, const int* in_sizes, int n_in,
                              void* d_out, int out_size, void* d_ws, size_t ws_size,
                              hipStream_t stream) {
    const float* x = (const float*)d_in[0];
    const int* ei = (const int*)d_in[1];
    const float* W0 = (const float*)d_in[2];
    const float* Wr = (const float*)d_in[3];
    const float* As = (const float*)d_in[4];
    const float* Ad = (const float*)d_in[5];
    const float* B = (const float*)d_in[6];
    float* out = (float*)d_out;

    char* p = (char*)d_ws;
    int* off = (int*)p;      p += alup((NN + 1) * sizeof(int));
    int* bcnt = (int*)p;     p += alup(256 * sizeof(int));
    int* boff = (int*)p;     p += alup(257 * sizeof(int));
    int* bcur = (int*)p;     p += alup(256 * sizeof(int));
    int2* pairs = (int2*)p;  p += alup((size_t)ETOT * sizeof(int2));
    int* ssrc = (int*)p;     p += alup((size_t)ETOT * sizeof(int));
    float* htmp = (float*)p; p += alup((size_t)NN * FF * sizeof(float));
    float* act = (float*)p;  p += alup((size_t)NN * FF * sizeof(float));
    float* as_ = (float*)p;  p += alup(NN * sizeof(float));
    float* ad_ = (float*)p;  p += alup(NN * sizeof(float));

    int gN = (NN + 255) / 256;

    hipMemsetAsync(bcnt, 0, 256 * sizeof(int), stream);
    k_bhist<<<512, 256, 0, stream>>>(ei, bcnt);
    k_bscan<<<1, 256, 0, stream>>>(bcnt, boff, bcur);
    k_bscatter<<<(ETOT + TILE - 1) / TILE, 256, 0, stream>>>(ei, bcur, pairs);
    k_bfill<<<NBUK, 256, 0, stream>>>(pairs, boff, off, ssrc);

    int gGemm = (25000 * 48 + 255) / 256;
    for (int l = 0; l < 5; l++) {
        if (l == 0)
            k_gemm<100><<<gGemm, 256, 0, stream>>>(x, W0, htmp);
        else
            k_gemm<48><<<gGemm, 256, 0, stream>>>(act, Wr + (size_t)(l - 1) * 48 * 48, htmp);
        k_alpha<<<gN, 256, 0, stream>>>(htmp, As + l * 48, Ad + l * 48, as_, ad_);
        k_aggr<<<(NN + 3) / 4, 256, 0, stream>>>(htmp, as_, ad_, off, ssrc, B + l * 48,
                                                 (l == 4) ? out : act);
    }
}

// Round 6
// 509.157 us; speedup vs baseline: 3.0341x; 1.2584x over previous
//
#include <hip/hip_runtime.h>

#define NN 100000
#define EE 1600000
#define ETOT (EE + NN)
#define FF 48
#define NEG 0.2f
#define BSH 9
#define BNODES 512                       // nodes per bucket = 1<<BSH
#define NBUK ((NN + BNODES - 1) / BNODES)  // 196
#define TILE 2048

// ---------------- bucketed CSR build ----------------

__global__ __launch_bounds__(256) void k_bhist(const int* __restrict__ ei,
                                               int* __restrict__ bcnt) {
    __shared__ int h[256];
    int t = threadIdx.x;
    h[t] = 0;
    __syncthreads();
    for (int i = blockIdx.x * 256 + t; i < ETOT; i += gridDim.x * 256) {
        int dd = (i < EE) ? ei[EE + i] : (i - EE);
        atomicAdd(&h[dd >> BSH], 1);
    }
    __syncthreads();
    if (h[t] > 0) atomicAdd(&bcnt[t], h[t]);
}

__global__ void k_bscan(const int* __restrict__ bcnt, int* __restrict__ boff,
                        int* __restrict__ bcur) {
    __shared__ int sb[256];
    int t = threadIdx.x;
    int v = (t < NBUK) ? bcnt[t] : 0;
    sb[t] = v;
    __syncthreads();
    for (int o = 1; o < 256; o <<= 1) {
        int x = (t >= o) ? sb[t - o] : 0;
        __syncthreads();
        sb[t] += x;
        __syncthreads();
    }
    int excl = sb[t] - v;
    boff[t] = excl;
    bcur[t] = excl;
}

__global__ __launch_bounds__(256) void k_bscatter(const int* __restrict__ ei,
                                                  int* __restrict__ bcur,
                                                  int2* __restrict__ pairs) {
    __shared__ int hist[256], incl[256], exc[256], curv[256], gb[256];
    __shared__ int2 stage[TILE];
    __shared__ int staddr[TILE];
    int t = threadIdx.x;
    hist[t] = 0;
    __syncthreads();
    int base = blockIdx.x * TILE;
    int s[8], d[8], b[8];
#pragma unroll
    for (int j = 0; j < 8; j++) {
        int i = base + t + j * 256;
        if (i < ETOT) {
            int ss, dd;
            if (i < EE) { ss = ei[i]; dd = ei[EE + i]; }
            else { ss = i - EE; dd = ss; }
            s[j] = ss; d[j] = dd; b[j] = dd >> BSH;
            atomicAdd(&hist[b[j]], 1);
        } else {
            b[j] = -1;
        }
    }
    __syncthreads();
    int hv = hist[t];
    incl[t] = hv;
    __syncthreads();
    for (int o = 1; o < 256; o <<= 1) {
        int x = (t >= o) ? incl[t - o] : 0;
        __syncthreads();
        incl[t] += x;
        __syncthreads();
    }
    int excl = incl[t] - hv;
    exc[t] = excl;
    curv[t] = excl;
    if (hv > 0) gb[t] = atomicAdd(&bcur[t], hv);
    __syncthreads();
    int total = incl[255];
#pragma unroll
    for (int j = 0; j < 8; j++) {
        if (b[j] >= 0) {
            int pos = atomicAdd(&curv[b[j]], 1);
            stage[pos] = make_int2(s[j], d[j]);
            staddr[pos] = gb[b[j]] + (pos - exc[b[j]]);
        }
    }
    __syncthreads();
    for (int i = t; i < total; i += 256) pairs[staddr[i]] = stage[i];
}

__global__ __launch_bounds__(256) void k_bfill(const int2* __restrict__ pairs,
                                               const int* __restrict__ boff,
                                               int* __restrict__ off,
                                               int* __restrict__ ssrc) {
    __shared__ int cnt[BNODES], cu[BNODES], sb[256];
    int blk = blockIdx.x;
    int t = threadIdx.x;
    int n0 = blk << BSH;
    int beg = boff[blk], end = boff[blk + 1];
    cnt[t] = 0;
    cnt[t + 256] = 0;
    __syncthreads();
    for (int i = beg + t; i < end; i += 256) {
        atomicAdd(&cnt[pairs[i].y - n0], 1);
    }
    __syncthreads();
    int c0 = cnt[2 * t], c1 = cnt[2 * t + 1];
    sb[t] = c0 + c1;
    __syncthreads();
    for (int o = 1; o < 256; o <<= 1) {
        int x = (t >= o) ? sb[t - o] : 0;
        __syncthreads();
        sb[t] += x;
        __syncthreads();
    }
    int e2 = sb[t] - (c0 + c1);
    cu[2 * t] = e2;
    cu[2 * t + 1] = e2 + c0;
    int n1 = min(n0 + BNODES, NN);
    if (n0 + 2 * t < n1) off[n0 + 2 * t] = beg + e2;
    if (n0 + 2 * t + 1 < n1) off[n0 + 2 * t + 1] = beg + e2 + c0;
    if (blk == 0 && t == 0) off[NN] = ETOT;
    __syncthreads();
    for (int i = beg + t; i < end; i += 256) {
        int2 pr = pairs[i];
        int pos = atomicAdd(&cu[pr.y - n0], 1);
        ssrc[beg + pos] = pr.x;
    }
}

// ---------------- fused GEMM + alpha ----------------
// Thread owns 2 rows x 12 features (fg = t&3 selects feature group).
// x loaded per-chunk as float4 into registers; W staged in LDS, read as 3
// broadcast ds_read_b128 per k. Epilogue computes alpha_s/alpha_d via
// per-lane partial dot + shfl_xor(1,2) reduction over the 4 fg lanes.
template <int K, int KC>
__global__ __launch_bounds__(256) void k_gemm(const float* __restrict__ in,
                                              const float* __restrict__ W,
                                              const float* __restrict__ a_s,
                                              const float* __restrict__ a_d,
                                              float* __restrict__ h,
                                              float* __restrict__ as_,
                                              float* __restrict__ ad_) {
    __shared__ float Wl[K * FF];
    __shared__ float asl[FF], adl[FF];
    int t = threadIdx.x;
    for (int i = t; i < K * FF / 4; i += 256)
        ((float4*)Wl)[i] = ((const float4*)W)[i];
    if (t < FF) { asl[t] = a_s[t]; adl[t] = a_d[t]; }
    __syncthreads();

    int fg = t & 3;
    int pr = t >> 2;
    int r0 = blockIdx.x * 128 + pr * 2;  // rows r0, r0+1 (NN even -> both valid if r0<NN)
    if (r0 >= NN) return;

    constexpr int NC = K / KC;
    constexpr int QC = KC / 4;
    const float4* x4 = (const float4*)in;
    const float4* wl4 = (const float4*)Wl;

    float acc0[12] = {0.f, 0.f, 0.f, 0.f, 0.f, 0.f, 0.f, 0.f, 0.f, 0.f, 0.f, 0.f};
    float acc1[12] = {0.f, 0.f, 0.f, 0.f, 0.f, 0.f, 0.f, 0.f, 0.f, 0.f, 0.f, 0.f};

    for (int c = 0; c < NC; c++) {
        float xs0[KC], xs1[KC];
#pragma unroll
        for (int q = 0; q < QC; q++) {
            float4 v0 = x4[(size_t)r0 * (K / 4) + c * QC + q];
            float4 v1 = x4[(size_t)(r0 + 1) * (K / 4) + c * QC + q];
            xs0[4 * q + 0] = v0.x; xs0[4 * q + 1] = v0.y;
            xs0[4 * q + 2] = v0.z; xs0[4 * q + 3] = v0.w;
            xs1[4 * q + 0] = v1.x; xs1[4 * q + 1] = v1.y;
            xs1[4 * q + 2] = v1.z; xs1[4 * q + 3] = v1.w;
        }
#pragma unroll
        for (int kk = 0; kk < KC; kk++) {
            const int k = c * KC + kk;
            const float xv0 = xs0[kk];
            const float xv1 = xs1[kk];
            const float4 w0 = wl4[k * 12 + fg * 3 + 0];
            const float4 w1 = wl4[k * 12 + fg * 3 + 1];
            const float4 w2 = wl4[k * 12 + fg * 3 + 2];
            acc0[0] = fmaf(xv0, w0.x, acc0[0]);  acc1[0] = fmaf(xv1, w0.x, acc1[0]);
            acc0[1] = fmaf(xv0, w0.y, acc0[1]);  acc1[1] = fmaf(xv1, w0.y, acc1[1]);
            acc0[2] = fmaf(xv0, w0.z, acc0[2]);  acc1[2] = fmaf(xv1, w0.z, acc1[2]);
            acc0[3] = fmaf(xv0, w0.w, acc0[3]);  acc1[3] = fmaf(xv1, w0.w, acc1[3]);
            acc0[4] = fmaf(xv0, w1.x, acc0[4]);  acc1[4] = fmaf(xv1, w1.x, acc1[4]);
            acc0[5] = fmaf(xv0, w1.y, acc0[5]);  acc1[5] = fmaf(xv1, w1.y, acc1[5]);
            acc0[6] = fmaf(xv0, w1.z, acc0[6]);  acc1[6] = fmaf(xv1, w1.z, acc1[6]);
            acc0[7] = fmaf(xv0, w1.w, acc0[7]);  acc1[7] = fmaf(xv1, w1.w, acc1[7]);
            acc0[8] = fmaf(xv0, w2.x, acc0[8]);  acc1[8] = fmaf(xv1, w2.x, acc1[8]);
            acc0[9] = fmaf(xv0, w2.y, acc0[9]);  acc1[9] = fmaf(xv1, w2.y, acc1[9]);
            acc0[10] = fmaf(xv0, w2.z, acc0[10]); acc1[10] = fmaf(xv1, w2.z, acc1[10]);
            acc0[11] = fmaf(xv0, w2.w, acc0[11]); acc1[11] = fmaf(xv1, w2.w, acc1[11]);
        }
    }

    // h writes (coalesced: lanes fg-fastest cover contiguous rows)
    float4* hp0 = (float4*)(h + (size_t)r0 * FF + fg * 12);
    float4* hp1 = (float4*)(h + (size_t)(r0 + 1) * FF + fg * 12);
    hp0[0] = make_float4(acc0[0], acc0[1], acc0[2], acc0[3]);
    hp0[1] = make_float4(acc0[4], acc0[5], acc0[6], acc0[7]);
    hp0[2] = make_float4(acc0[8], acc0[9], acc0[10], acc0[11]);
    hp1[0] = make_float4(acc1[0], acc1[1], acc1[2], acc1[3]);
    hp1[1] = make_float4(acc1[4], acc1[5], acc1[6], acc1[7]);
    hp1[2] = make_float4(acc1[8], acc1[9], acc1[10], acc1[11]);

    // fused alpha: partial dots over this lane's 12 features, reduce over fg
    float ps0 = 0.f, pd0 = 0.f, ps1 = 0.f, pd1 = 0.f;
#pragma unroll
    for (int j = 0; j < 12; j++) {
        float av = asl[fg * 12 + j], dv = adl[fg * 12 + j];
        ps0 = fmaf(acc0[j], av, ps0);
        pd0 = fmaf(acc0[j], dv, pd0);
        ps1 = fmaf(acc1[j], av, ps1);
        pd1 = fmaf(acc1[j], dv, pd1);
    }
    ps0 += __shfl_xor(ps0, 1); ps0 += __shfl_xor(ps0, 2);
    pd0 += __shfl_xor(pd0, 1); pd0 += __shfl_xor(pd0, 2);
    ps1 += __shfl_xor(ps1, 1); ps1 += __shfl_xor(ps1, 2);
    pd1 += __shfl_xor(pd1, 1); pd1 += __shfl_xor(pd1, 2);
    if (fg == 0) {
        as_[r0] = ps0; ad_[r0] = pd0;
        as_[r0 + 1] = ps1; ad_[r0 + 1] = pd1;
    }
}

// ---------------- aggregation (unchanged from R4) ----------------

__global__ __launch_bounds__(256) void k_aggr(const float* __restrict__ h,
                                              const float* __restrict__ as_,
                                              const float* __restrict__ ad_,
                                              const int* __restrict__ off,
                                              const int* __restrict__ ssrc,
                                              const float* __restrict__ bias,
                                              float* __restrict__ out) {
    int wave = threadIdx.x >> 6;
    int lane = threadIdx.x & 63;
    int d = blockIdx.x * 4 + wave;
    if (d >= NN) return;
    int beg = off[d], end = off[d + 1];
    int deg = end - beg;
    float add = ad_[d];
    int f = lane;

    float acc = 0.f, s = 0.f;

    if (deg <= 64) {
        int src = 0;
        float e = -1e30f;
        if (lane < deg) {
            src = ssrc[beg + lane];
            float t = as_[src] + add;
            e = (t > 0.f) ? t : NEG * t;
        }
        float m = e;
#pragma unroll
        for (int o = 32; o; o >>= 1) m = fmaxf(m, __shfl_xor(m, o));
        float p = (lane < deg) ? __expf(e - m) : 0.f;

        int i = 0;
        for (; i + 4 <= deg; i += 4) {
            float p0 = __shfl(p, i), p1 = __shfl(p, i + 1);
            float p2 = __shfl(p, i + 2), p3 = __shfl(p, i + 3);
            int s0 = __shfl(src, i), s1 = __shfl(src, i + 1);
            int s2 = __shfl(src, i + 2), s3 = __shfl(src, i + 3);
            float h0 = 0.f, h1 = 0.f, h2 = 0.f, h3 = 0.f;
            if (f < FF) {
                h0 = h[(size_t)s0 * FF + f];
                h1 = h[(size_t)s1 * FF + f];
                h2 = h[(size_t)s2 * FF + f];
                h3 = h[(size_t)s3 * FF + f];
            }
            s += p0; s += p1; s += p2; s += p3;
            if (f < FF) {
                acc = fmaf(p0, h0, acc);
                acc = fmaf(p1, h1, acc);
                acc = fmaf(p2, h2, acc);
                acc = fmaf(p3, h3, acc);
            }
        }
        for (; i < deg; i++) {
            float pi = __shfl(p, i);
            int si = __shfl(src, i);
            s += pi;
            if (f < FF) acc = fmaf(pi, h[(size_t)si * FF + f], acc);
        }
    } else {
        float m = -1e30f;
        for (int i = beg + lane; i < end; i += 64) {
            float t = as_[ssrc[i]] + add;
            t = (t > 0.f) ? t : NEG * t;
            m = fmaxf(m, t);
        }
#pragma unroll
        for (int o = 32; o; o >>= 1) m = fmaxf(m, __shfl_xor(m, o));
        for (int i = beg; i < end; i++) {
            int src = ssrc[i];
            float e = as_[src] + add;
            e = (e > 0.f) ? e : NEG * e;
            float pp = __expf(e - m);
            s += pp;
            if (f < FF) acc = fmaf(pp, h[(size_t)src * FF + f], acc);
        }
    }

    if (f < FF) {
        float v = acc / fmaxf(s, 1e-16f) + bias[f];
        v = (v > 0.f) ? v : (__expf(v) - 1.0f);  // ELU
        out[(size_t)d * FF + f] = v;
    }
}

// ---------------- launcher ----------------

static inline size_t alup(size_t x) { return (x + 255) & ~(size_t)255; }

extern "C" void kernel_launch(void* const* d_in, const int* in_sizes, int n_in,
                              void* d_out, int out_size, void* d_ws, size_t ws_size,
                              hipStream_t stream) {
    const float* x = (const float*)d_in[0];
    const int* ei = (const int*)d_in[1];
    const float* W0 = (const float*)d_in[2];
    const float* Wr = (const float*)d_in[3];
    const float* As = (const float*)d_in[4];
    const float* Ad = (const float*)d_in[5];
    const float* B = (const float*)d_in[6];
    float* out = (float*)d_out;

    char* p = (char*)d_ws;
    int* off = (int*)p;      p += alup((NN + 1) * sizeof(int));
    int* bcnt = (int*)p;     p += alup(256 * sizeof(int));
    int* boff = (int*)p;     p += alup(257 * sizeof(int));
    int* bcur = (int*)p;     p += alup(256 * sizeof(int));
    int2* pairs = (int2*)p;  p += alup((size_t)ETOT * sizeof(int2));
    int* ssrc = (int*)p;     p += alup((size_t)ETOT * sizeof(int));
    float* htmp = (float*)p; p += alup((size_t)NN * FF * sizeof(float));
    float* act = (float*)p;  p += alup((size_t)NN * FF * sizeof(float));
    float* as_ = (float*)p;  p += alup(NN * sizeof(float));
    float* ad_ = (float*)p;  p += alup(NN * sizeof(float));

    hipMemsetAsync(bcnt, 0, 256 * sizeof(int), stream);
    k_bhist<<<512, 256, 0, stream>>>(ei, bcnt);
    k_bscan<<<1, 256, 0, stream>>>(bcnt, boff, bcur);
    k_bscatter<<<(ETOT + TILE - 1) / TILE, 256, 0, stream>>>(ei, bcur, pairs);
    k_bfill<<<NBUK, 256, 0, stream>>>(pairs, boff, off, ssrc);

    int gGemm = (NN + 127) / 128;
    for (int l = 0; l < 5; l++) {
        if (l == 0)
            k_gemm<100, 20><<<gGemm, 256, 0, stream>>>(x, W0, As, Ad, htmp, as_, ad_);
        else
            k_gemm<48, 16><<<gGemm, 256, 0, stream>>>(act, Wr + (size_t)(l - 1) * 48 * 48,
                                                      As + l * 48, Ad + l * 48, htmp, as_, ad_);
        k_aggr<<<(NN + 3) / 4, 256, 0, stream>>>(htmp, as_, ad_, off, ssrc, B + l * 48,
                                                 (l == 4) ? out : act);
    }
}

// Round 7
// 486.405 us; speedup vs baseline: 3.1760x; 1.0468x over previous
//
#include <hip/hip_runtime.h>

#define NN 100000
#define EE 1600000
#define ETOT (EE + NN)
#define FF 48
#define NEG 0.2f
#define BSH 9
#define BNODES 512                       // nodes per bucket = 1<<BSH
#define NBUK ((NN + BNODES - 1) / BNODES)  // 196
#define TILE 2048

// ---------------- bucketed CSR build ----------------

__global__ __launch_bounds__(256) void k_bhist(const int* __restrict__ ei,
                                               int* __restrict__ bcnt) {
    __shared__ int h[256];
    int t = threadIdx.x;
    h[t] = 0;
    __syncthreads();
    for (int i = blockIdx.x * 256 + t; i < ETOT; i += gridDim.x * 256) {
        int dd = (i < EE) ? ei[EE + i] : (i - EE);
        atomicAdd(&h[dd >> BSH], 1);
    }
    __syncthreads();
    if (h[t] > 0) atomicAdd(&bcnt[t], h[t]);
}

__global__ void k_bscan(const int* __restrict__ bcnt, int* __restrict__ boff,
                        int* __restrict__ bcur) {
    __shared__ int sb[256];
    int t = threadIdx.x;
    int v = (t < NBUK) ? bcnt[t] : 0;
    sb[t] = v;
    __syncthreads();
    for (int o = 1; o < 256; o <<= 1) {
        int x = (t >= o) ? sb[t - o] : 0;
        __syncthreads();
        sb[t] += x;
        __syncthreads();
    }
    int excl = sb[t] - v;
    boff[t] = excl;
    bcur[t] = excl;
}

__global__ __launch_bounds__(256) void k_bscatter(const int* __restrict__ ei,
                                                  int* __restrict__ bcur,
                                                  int2* __restrict__ pairs) {
    __shared__ int hist[256], incl[256], exc[256], curv[256], gb[256];
    __shared__ int2 stage[TILE];
    __shared__ int staddr[TILE];
    int t = threadIdx.x;
    hist[t] = 0;
    __syncthreads();
    int base = blockIdx.x * TILE;
    int s[8], d[8], b[8];
#pragma unroll
    for (int j = 0; j < 8; j++) {
        int i = base + t + j * 256;
        if (i < ETOT) {
            int ss, dd;
            if (i < EE) { ss = ei[i]; dd = ei[EE + i]; }
            else { ss = i - EE; dd = ss; }
            s[j] = ss; d[j] = dd; b[j] = dd >> BSH;
            atomicAdd(&hist[b[j]], 1);
        } else {
            b[j] = -1;
        }
    }
    __syncthreads();
    int hv = hist[t];
    incl[t] = hv;
    __syncthreads();
    for (int o = 1; o < 256; o <<= 1) {
        int x = (t >= o) ? incl[t - o] : 0;
        __syncthreads();
        incl[t] += x;
        __syncthreads();
    }
    int excl = incl[t] - hv;
    exc[t] = excl;
    curv[t] = excl;
    if (hv > 0) gb[t] = atomicAdd(&bcur[t], hv);
    __syncthreads();
    int total = incl[255];
#pragma unroll
    for (int j = 0; j < 8; j++) {
        if (b[j] >= 0) {
            int pos = atomicAdd(&curv[b[j]], 1);
            stage[pos] = make_int2(s[j], d[j]);
            staddr[pos] = gb[b[j]] + (pos - exc[b[j]]);
        }
    }
    __syncthreads();
    for (int i = t; i < total; i += 256) pairs[staddr[i]] = stage[i];
}

__global__ __launch_bounds__(256) void k_bfill(const int2* __restrict__ pairs,
                                               const int* __restrict__ boff,
                                               int* __restrict__ off,
                                               int* __restrict__ ssrc) {
    __shared__ int cnt[BNODES], cu[BNODES], sb[256];
    int blk = blockIdx.x;
    int t = threadIdx.x;
    int n0 = blk << BSH;
    int beg = boff[blk], end = boff[blk + 1];
    cnt[t] = 0;
    cnt[t + 256] = 0;
    __syncthreads();
    for (int i = beg + t; i < end; i += 256) {
        atomicAdd(&cnt[pairs[i].y - n0], 1);
    }
    __syncthreads();
    int c0 = cnt[2 * t], c1 = cnt[2 * t + 1];
    sb[t] = c0 + c1;
    __syncthreads();
    for (int o = 1; o < 256; o <<= 1) {
        int x = (t >= o) ? sb[t - o] : 0;
        __syncthreads();
        sb[t] += x;
        __syncthreads();
    }
    int e2 = sb[t] - (c0 + c1);
    cu[2 * t] = e2;
    cu[2 * t + 1] = e2 + c0;
    int n1 = min(n0 + BNODES, NN);
    if (n0 + 2 * t < n1) off[n0 + 2 * t] = beg + e2;
    if (n0 + 2 * t + 1 < n1) off[n0 + 2 * t + 1] = beg + e2 + c0;
    if (blk == 0 && t == 0) off[NN] = ETOT;
    __syncthreads();
    for (int i = beg + t; i < end; i += 256) {
        int2 pr = pairs[i];
        int pos = atomicAdd(&cu[pr.y - n0], 1);
        ssrc[beg + pos] = pr.x;
    }
}

// ---------------- fused GEMM + alpha (unchanged from R6) ----------------

template <int K, int KC>
__global__ __launch_bounds__(256) void k_gemm(const float* __restrict__ in,
                                              const float* __restrict__ W,
                                              const float* __restrict__ a_s,
                                              const float* __restrict__ a_d,
                                              float* __restrict__ h,
                                              float* __restrict__ as_,
                                              float* __restrict__ ad_) {
    __shared__ float Wl[K * FF];
    __shared__ float asl[FF], adl[FF];
    int t = threadIdx.x;
    for (int i = t; i < K * FF / 4; i += 256)
        ((float4*)Wl)[i] = ((const float4*)W)[i];
    if (t < FF) { asl[t] = a_s[t]; adl[t] = a_d[t]; }
    __syncthreads();

    int fg = t & 3;
    int pr = t >> 2;
    int r0 = blockIdx.x * 128 + pr * 2;
    if (r0 >= NN) return;

    constexpr int NC = K / KC;
    constexpr int QC = KC / 4;
    const float4* x4 = (const float4*)in;
    const float4* wl4 = (const float4*)Wl;

    float acc0[12] = {0.f, 0.f, 0.f, 0.f, 0.f, 0.f, 0.f, 0.f, 0.f, 0.f, 0.f, 0.f};
    float acc1[12] = {0.f, 0.f, 0.f, 0.f, 0.f, 0.f, 0.f, 0.f, 0.f, 0.f, 0.f, 0.f};

    for (int c = 0; c < NC; c++) {
        float xs0[KC], xs1[KC];
#pragma unroll
        for (int q = 0; q < QC; q++) {
            float4 v0 = x4[(size_t)r0 * (K / 4) + c * QC + q];
            float4 v1 = x4[(size_t)(r0 + 1) * (K / 4) + c * QC + q];
            xs0[4 * q + 0] = v0.x; xs0[4 * q + 1] = v0.y;
            xs0[4 * q + 2] = v0.z; xs0[4 * q + 3] = v0.w;
            xs1[4 * q + 0] = v1.x; xs1[4 * q + 1] = v1.y;
            xs1[4 * q + 2] = v1.z; xs1[4 * q + 3] = v1.w;
        }
#pragma unroll
        for (int kk = 0; kk < KC; kk++) {
            const int k = c * KC + kk;
            const float xv0 = xs0[kk];
            const float xv1 = xs1[kk];
            const float4 w0 = wl4[k * 12 + fg * 3 + 0];
            const float4 w1 = wl4[k * 12 + fg * 3 + 1];
            const float4 w2 = wl4[k * 12 + fg * 3 + 2];
            acc0[0] = fmaf(xv0, w0.x, acc0[0]);  acc1[0] = fmaf(xv1, w0.x, acc1[0]);
            acc0[1] = fmaf(xv0, w0.y, acc0[1]);  acc1[1] = fmaf(xv1, w0.y, acc1[1]);
            acc0[2] = fmaf(xv0, w0.z, acc0[2]);  acc1[2] = fmaf(xv1, w0.z, acc1[2]);
            acc0[3] = fmaf(xv0, w0.w, acc0[3]);  acc1[3] = fmaf(xv1, w0.w, acc1[3]);
            acc0[4] = fmaf(xv0, w1.x, acc0[4]);  acc1[4] = fmaf(xv1, w1.x, acc1[4]);
            acc0[5] = fmaf(xv0, w1.y, acc0[5]);  acc1[5] = fmaf(xv1, w1.y, acc1[5]);
            acc0[6] = fmaf(xv0, w1.z, acc0[6]);  acc1[6] = fmaf(xv1, w1.z, acc1[6]);
            acc0[7] = fmaf(xv0, w1.w, acc0[7]);  acc1[7] = fmaf(xv1, w1.w, acc1[7]);
            acc0[8] = fmaf(xv0, w2.x, acc0[8]);  acc1[8] = fmaf(xv1, w2.x, acc1[8]);
            acc0[9] = fmaf(xv0, w2.y, acc0[9]);  acc1[9] = fmaf(xv1, w2.y, acc1[9]);
            acc0[10] = fmaf(xv0, w2.z, acc0[10]); acc1[10] = fmaf(xv1, w2.z, acc1[10]);
            acc0[11] = fmaf(xv0, w2.w, acc0[11]); acc1[11] = fmaf(xv1, w2.w, acc1[11]);
        }
    }

    float4* hp0 = (float4*)(h + (size_t)r0 * FF + fg * 12);
    float4* hp1 = (float4*)(h + (size_t)(r0 + 1) * FF + fg * 12);
    hp0[0] = make_float4(acc0[0], acc0[1], acc0[2], acc0[3]);
    hp0[1] = make_float4(acc0[4], acc0[5], acc0[6], acc0[7]);
    hp0[2] = make_float4(acc0[8], acc0[9], acc0[10], acc0[11]);
    hp1[0] = make_float4(acc1[0], acc1[1], acc1[2], acc1[3]);
    hp1[1] = make_float4(acc1[4], acc1[5], acc1[6], acc1[7]);
    hp1[2] = make_float4(acc1[8], acc1[9], acc1[10], acc1[11]);

    float ps0 = 0.f, pd0 = 0.f, ps1 = 0.f, pd1 = 0.f;
#pragma unroll
    for (int j = 0; j < 12; j++) {
        float av = asl[fg * 12 + j], dv = adl[fg * 12 + j];
        ps0 = fmaf(acc0[j], av, ps0);
        pd0 = fmaf(acc0[j], dv, pd0);
        ps1 = fmaf(acc1[j], av, ps1);
        pd1 = fmaf(acc1[j], dv, pd1);
    }
    ps0 += __shfl_xor(ps0, 1); ps0 += __shfl_xor(ps0, 2);
    pd0 += __shfl_xor(pd0, 1); pd0 += __shfl_xor(pd0, 2);
    ps1 += __shfl_xor(ps1, 1); ps1 += __shfl_xor(ps1, 2);
    pd1 += __shfl_xor(pd1, 1); pd1 += __shfl_xor(pd1, 2);
    if (fg == 0) {
        as_[r0] = ps0; ad_[r0] = pd0;
        as_[r0 + 1] = ps1; ad_[r0 + 1] = pd1;
    }
}

// ---------------- aggregation ----------------
// One wave per dst. Fast path: p/src broadcast via v_readlane into SGPRs
// (uniform index), 8 independent h-gathers in flight; deg padded to x8 with
// p=0 slots; sum-of-p via one butterfly. Edge accumulation order == R4.
__global__ __launch_bounds__(256) void k_aggr(const float* __restrict__ h,
                                              const float* __restrict__ as_,
                                              const float* __restrict__ ad_,
                                              const int* __restrict__ off,
                                              const int* __restrict__ ssrc,
                                              const float* __restrict__ bias,
                                              float* __restrict__ out) {
    int wave = threadIdx.x >> 6;
    int lane = threadIdx.x & 63;
    int d = blockIdx.x * 4 + wave;
    if (d >= NN) return;
    int beg = __builtin_amdgcn_readfirstlane(off[d]);
    int end = __builtin_amdgcn_readfirstlane(off[d + 1]);
    int deg = end - beg;
    float add = ad_[d];
    int f = lane;

    float acc = 0.f, s = 0.f;

    if (deg <= 64) {
        int srcb = 0;
        float e = -1e30f;
        if (lane < deg) {
            int src = ssrc[beg + lane];
            srcb = src * (FF * 4);
            float t = as_[src] + add;
            e = (t > 0.f) ? t : NEG * t;
        }
        float m = e;
#pragma unroll
        for (int o = 32; o; o >>= 1) m = fmaxf(m, __shfl_xor(m, o));
        float p = (lane < deg) ? __expf(e - m) : 0.f;
        float sv = p;
#pragma unroll
        for (int o = 32; o; o >>= 1) sv += __shfl_xor(sv, o);
        s = sv;

        const char* hb = (const char*)h;
        unsigned pbits = __float_as_uint(p);
        int degR = (deg + 7) & ~7;
        for (int i = 0; i < degR; i += 8) {
#pragma unroll
            for (int j = 0; j < 8; j++) {
                float pj = __uint_as_float(
                    (unsigned)__builtin_amdgcn_readlane((int)pbits, i + j));
                int sbj = __builtin_amdgcn_readlane(srcb, i + j);
                float hv = 0.f;
                if (f < FF) hv = *(const float*)(hb + sbj + 4 * f);
                acc = fmaf(pj, hv, acc);
            }
        }
    } else {
        // general path (never taken for this graph)
        float m = -1e30f;
        for (int i = beg + lane; i < end; i += 64) {
            float t = as_[ssrc[i]] + add;
            t = (t > 0.f) ? t : NEG * t;
            m = fmaxf(m, t);
        }
#pragma unroll
        for (int o = 32; o; o >>= 1) m = fmaxf(m, __shfl_xor(m, o));
        for (int i = beg; i < end; i++) {
            int src = ssrc[i];
            float e = as_[src] + add;
            e = (e > 0.f) ? e : NEG * e;
            float pp = __expf(e - m);
            s += pp;
            if (f < FF) acc = fmaf(pp, h[(size_t)src * FF + f], acc);
        }
    }

    if (f < FF) {
        float v = acc / fmaxf(s, 1e-16f) + bias[f];
        v = (v > 0.f) ? v : (__expf(v) - 1.0f);  // ELU
        out[(size_t)d * FF + f] = v;
    }
}

// ---------------- launcher ----------------

static inline size_t alup(size_t x) { return (x + 255) & ~(size_t)255; }

extern "C" void kernel_launch(void* const* d_in, const int* in_sizes, int n_in,
                              void* d_out, int out_size, void* d_ws, size_t ws_size,
                              hipStream_t stream) {
    const float* x = (const float*)d_in[0];
    const int* ei = (const int*)d_in[1];
    const float* W0 = (const float*)d_in[2];
    const float* Wr = (const float*)d_in[3];
    const float* As = (const float*)d_in[4];
    const float* Ad = (const float*)d_in[5];
    const float* B = (const float*)d_in[6];
    float* out = (float*)d_out;

    char* p = (char*)d_ws;
    int* off = (int*)p;      p += alup((NN + 1) * sizeof(int));
    int* bcnt = (int*)p;     p += alup(256 * sizeof(int));
    int* boff = (int*)p;     p += alup(257 * sizeof(int));
    int* bcur = (int*)p;     p += alup(256 * sizeof(int));
    int2* pairs = (int2*)p;  p += alup((size_t)ETOT * sizeof(int2));
    int* ssrc = (int*)p;     p += alup((size_t)ETOT * sizeof(int));
    float* htmp = (float*)p; p += alup((size_t)NN * FF * sizeof(float));
    float* act = (float*)p;  p += alup((size_t)NN * FF * sizeof(float));
    float* as_ = (float*)p;  p += alup(NN * sizeof(float));
    float* ad_ = (float*)p;  p += alup(NN * sizeof(float));

    hipMemsetAsync(bcnt, 0, 256 * sizeof(int), stream);
    k_bhist<<<512, 256, 0, stream>>>(ei, bcnt);
    k_bscan<<<1, 256, 0, stream>>>(bcnt, boff, bcur);
    k_bscatter<<<(ETOT + TILE - 1) / TILE, 256, 0, stream>>>(ei, bcur, pairs);
    k_bfill<<<NBUK, 256, 0, stream>>>(pairs, boff, off, ssrc);

    int gGemm = (NN + 127) / 128;
    for (int l = 0; l < 5; l++) {
        if (l == 0)
            k_gemm<100, 20><<<gGemm, 256, 0, stream>>>(x, W0, As, Ad, htmp, as_, ad_);
        else
            k_gemm<48, 16><<<gGemm, 256, 0, stream>>>(act, Wr + (size_t)(l - 1) * 48 * 48,
                                                      As + l * 48, Ad + l * 48, htmp, as_, ad_);
        k_aggr<<<(NN + 3) / 4, 256, 0, stream>>>(htmp, as_, ad_, off, ssrc, B + l * 48,
                                                 (l == 4) ? out : act);
    }
}